// Round 11
// baseline (116.852 us; speedup 1.0000x reference)
//
#include <hip/hip_runtime.h>
#include <hip/hip_bf16.h>

#define ROWS 64
#define CELLS 64
#define CN_LEN 8
#define CV_LEN 16
#define EMB 768
#define HID 3072
#define NCELL 4096
#define L_CV 1024
#define ROW_TOK 1089  /* 1 cls + 64 cn + 1024 cv */
#define HBLK 24       /* 3072/128 h-blocks in gate GEMM */
#define FILL_CHUNKS 96 /* per-row flat fill chunks of 8192 floats */

// ---- workspace layout (bytes), no zero-init required anywhere ----
#define OFF_FPART 0UL                             /* 96*8 f32 fgate partials */
#define OFF_GPART (OFF_FPART + 96UL*8*4)          /* 24*4096 f32 gemm partials */
#define OFF_CNB   (OFF_GPART + 24UL*4096*4)       /* 4096x768 fp8 */
#define OFF_W1T   (OFF_CNB + 4096UL*768)          /* 3072x768 fp8 (gate_w1^T) */
#define OFF_CST   (OFF_W1T + 3072UL*768)          /* 4096 int per-cell start */
#define OFF_CNT   (OFF_CST + 4096UL*4)            /* 64 int per-row count */

typedef __attribute__((ext_vector_type(4))) float f32x4;

static __device__ __forceinline__ unsigned f2fp8x4(float x, float y, float z,
                                                   float w) {
  int p = __builtin_amdgcn_cvt_pk_fp8_f32(x, y, 0, 0);       // bytes 0,1
  p = __builtin_amdgcn_cvt_pk_fp8_f32(z, w, p, 1);           // bytes 2,3
  return (unsigned)p;
}

static __device__ __forceinline__ unsigned char f2fp8(float x) {
  return (unsigned char)(__builtin_amdgcn_cvt_pk_fp8_f32(x, 0.f, 0, 0) & 0xff);
}

static __device__ __forceinline__ void gload16(const void* g, void* l) {
  __builtin_amdgcn_global_load_lds(
      (const __attribute__((address_space(1))) unsigned*)g,
      (__attribute__((address_space(3))) unsigned*)l, 16, 0, 0);
}

// ---------- prep: blocks 0..95 fgate partials | 96..159 cv prefix ----------
__global__ __launch_bounds__(512) void k_prep(
    const float* __restrict__ type_emb, const float* __restrict__ fuse_w1,
    const float* __restrict__ fuse_b1, const float* __restrict__ fuse_w2,
    float* __restrict__ fpart, const int* __restrict__ cv_mask,
    int* __restrict__ cstart, int* __restrict__ cnt) {
  const int tid = threadIdx.x;
  const int b = blockIdx.x;
  if (b >= 96) {
    // ---- prefix scan over one row's 1024 cv_mask values ----
    __shared__ int ssum[512];
    const int row = b - 96;
    const int base = row * L_CV + tid * 2;
    const int m0 = cv_mask[base], m1 = cv_mask[base + 1];
    const int s = m0 + m1;
    ssum[tid] = s;
    __syncthreads();
    for (int off = 1; off < 512; off <<= 1) {
      int v = (tid >= off) ? ssum[tid - off] : 0;
      __syncthreads();
      ssum[tid] += v;
      __syncthreads();
    }
    if ((tid & 7) == 0) cstart[row * CELLS + (tid >> 3)] = ssum[tid] - s;
    if (tid == 511) cnt[row] = ssum[511];
    return;
  }
  // ---- fgate: 8-type register reuse, w1 read once ----
  __shared__ float te[8 * EMB];      // 24 KB
  __shared__ float red[16][8][33];
  for (int i = tid; i < 8 * EMB; i += 512) te[i] = type_emb[i];
  __syncthreads();
  const int hl = tid & 31, eg = tid >> 5;  // eg in 0..15, 48 e's each
  const int h = b * 32 + hl;
  float acc[8] = {0.f, 0.f, 0.f, 0.f, 0.f, 0.f, 0.f, 0.f};
  const float* wp = fuse_w1 + h;
  #pragma unroll 4
  for (int i = 0; i < 48; i++) {
    const int e = eg * 48 + i;
    const float wv = wp[(size_t)e * HID];
    #pragma unroll
    for (int t = 0; t < 8; t++) acc[t] += te[t * EMB + e] * wv;
  }
  #pragma unroll
  for (int t = 0; t < 8; t++) red[eg][t][hl] = acc[t];
  __syncthreads();
  if (tid < 256) {
    const int t = tid >> 5, h2 = tid & 31;
    float a = fuse_b1[b * 32 + h2];
    #pragma unroll
    for (int e2 = 0; e2 < 16; e2++) a += red[e2][t][h2];
    float v = fmaxf(a, 0.f) * fuse_w2[b * 32 + h2];
    #pragma unroll
    for (int m = 1; m < 32; m <<= 1) v += __shfl_xor(v, m);
    if (h2 == 0) fpart[b * 8 + t] = v;  // each slot written once
  }
}

// ---------- cn_e (blocks 0..4095) + w1t transpose (blocks 4096..4863) ----------
__global__ __launch_bounds__(192) void k_cn(
    const int* __restrict__ cn_ids, const int* __restrict__ cn_mask,
    const int* __restrict__ c_types, const float* __restrict__ word_emb,
    const float* __restrict__ type_emb, const float* __restrict__ cls_w,
    const float* __restrict__ fpart, const float* __restrict__ fuse_b2,
    const float* __restrict__ w1, unsigned char* __restrict__ w1t,
    unsigned char* __restrict__ cnb, float* __restrict__ out) {
  __shared__ float tile[32][97];
  const int tid = threadIdx.x;
  if (blockIdx.x >= NCELL) {
    // ---- w1t: transpose+fp8 a 96(h) x 32(e) region ----
    const int wb = blockIdx.x - NCELL;
    const int ht = wb & 31, et = wb >> 5;   // ht: 96-wide h tile, et: 32-wide e tile
    const int hi = tid >= 96 ? 1 : 0, cc = tid - 96 * hi;
    #pragma unroll
    for (int i = 0; i < 16; i++) {
      const int rr = i * 2 + hi;
      tile[rr][cc] = w1[(size_t)(et * 32 + rr) * HID + ht * 96 + cc];
    }
    __syncthreads();
    const int rfrac = tid >> 5, cc2 = tid & 31;
    #pragma unroll
    for (int i = 0; i < 16; i++) {
      const int rr2 = i * 6 + rfrac;
      w1t[(size_t)(ht * 96 + rr2) * EMB + et * 32 + cc2] = f2fp8(tile[cc2][rr2]);
    }
    return;
  }
  const int n = blockIdx.x;
  const int row = n >> 6, cell = n & 63;
  const int* ids = cn_ids + n * CN_LEN;
  const int* msk = cn_mask + n * CN_LEN;
  float4 s = {0.f, 0.f, 0.f, 0.f};
  int cnt = 0;
  #pragma unroll
  for (int j = 0; j < CN_LEN; j++) {
    if (msk[j]) {
      cnt++;
      const float4 v = *(const float4*)&word_emb[(size_t)ids[j] * EMB + tid * 4];
      s.x += v.x; s.y += v.y; s.z += v.z; s.w += v.w;
    }
  }
  const float inv = 1.f / (float)cnt;
  const int t = c_types[n];
  float sg = fuse_b2[0];
  #pragma unroll 8
  for (int j = 0; j < 96; j++) sg += fpart[j * 8 + t];
  const float fg = 1.f / (1.f + expf(-sg));
  const float4 d = *(const float4*)&type_emb[(size_t)t * EMB + tid * 4];
  float4 c;
  c.x = s.x * inv + d.x * fg;
  c.y = s.y * inv + d.y * fg;
  c.z = s.z * inv + d.z * fg;
  c.w = s.w * inv + d.w * fg;
  *(unsigned*)&cnb[(size_t)n * EMB + tid * 4] = f2fp8x4(c.x, c.y, c.z, c.w);
  *(float4*)&out[(size_t)row * ROW_TOK * EMB + (size_t)(1 + cell) * EMB + tid * 4] = c;
  if (cell == 0)
    *(float4*)&out[(size_t)row * ROW_TOK * EMB + tid * 4] =
        *(const float4*)&cls_w[tid * 4];
}

// ---------- gate GEMM fp8 (blocks 0..767) + cv tail zero-fill (768..) ----------
__global__ __launch_bounds__(256) void k_gate_gemm(
    const unsigned char* __restrict__ cnb, const unsigned char* __restrict__ w1t,
    const float* __restrict__ gate_b1, const float* __restrict__ gate_w2,
    float* __restrict__ gpart, const int* __restrict__ cnt,
    float* __restrict__ out) {
  __shared__ unsigned char Asub[2][128 * 32];   // 2 x 4 KB
  __shared__ unsigned char Bsub[2][128 * 32];   // 2 x 4 KB
  const int tid = threadIdx.x;
  if (blockIdx.x >= 768) {
    // ---- flat zero-fill of cv tail: row, 8192-float chunk ----
    const int fb = blockIdx.x - 768;
    const int row = fb / FILL_CHUNKS, chunk = fb % FILL_CHUNKS;
    const int lim = cnt[row] * EMB;            // fill floats at idx >= lim
    const int c0 = chunk * 8192;
    if (c0 + 8192 <= lim) return;              // chunk entirely value-covered
    const size_t base = (size_t)row * ROW_TOK * EMB + 65UL * EMB;
    const float4 z = {0.f, 0.f, 0.f, 0.f};
    #pragma unroll
    for (int i = 0; i < 8; i++) {
      const int idx = c0 + i * 1024 + tid * 4;
      if (idx >= lim) *(float4*)&out[base + idx] = z;
    }
    return;
  }
  // bijective XCD swizzle: 768 blocks, 96 consecutive per XCD -> same-by chunks
  const int orig = blockIdx.x;
  const int wgid = (orig & 7) * 96 + (orig >> 3);
  const int bx = wgid & 31, by = wgid >> 5;   // bx: n-tile 0..31, by: h-tile 0..23
  const int n0 = bx * 128, h0 = by * 128;
  const int lane = tid & 63, w = tid >> 6;
  const int wr = w >> 1, wc = w & 1;
  const int r = lane & 15, g = lane >> 4;
  f32x4 acc[4][4];
  #pragma unroll
  for (int a = 0; a < 4; a++)
    #pragma unroll
    for (int b = 0; b < 4; b++) acc[a][b] = (f32x4)0.f;

  // staging: 256 slots of 16B per matrix; thread -> row tid>>1, 16B-chunk tid&1
  const int ar = tid >> 1, ac = (tid & 1) * 16;
  const unsigned char* aB = cnb + (size_t)n0 * EMB;
  const unsigned char* bB = w1t + (size_t)h0 * EMB;

#define STAGE(buf, kk)                                                    \
  do {                                                                    \
    gload16(aB + (size_t)ar * EMB + (kk) + ac, &Asub[buf][ar * 32 + ac]); \
    gload16(bB + (size_t)ar * EMB + (kk) + ac, &Bsub[buf][ar * 32 + ac]); \
  } while (0)

#define COMPUTE(buf)                                                          \
  do {                                                                        \
    long fa[4], fb[4];                                                        \
    _Pragma("unroll")                                                         \
    for (int fm = 0; fm < 4; fm++)                                            \
      fa[fm] = *(const long*)&Asub[buf][(wr * 64 + fm * 16 + r) * 32 + g * 8]; \
    _Pragma("unroll")                                                         \
    for (int fn = 0; fn < 4; fn++)                                            \
      fb[fn] = *(const long*)&Bsub[buf][(wc * 64 + fn * 16 + r) * 32 + g * 8]; \
    _Pragma("unroll")                                                         \
    for (int fm = 0; fm < 4; fm++)                                            \
      _Pragma("unroll")                                                       \
      for (int fn = 0; fn < 4; fn++)                                          \
        acc[fm][fn] = __builtin_amdgcn_mfma_f32_16x16x32_fp8_fp8(             \
            fa[fm], fb[fn], acc[fm][fn], 0, 0, 0);                            \
  } while (0)

  STAGE(0, 0);
  __syncthreads();
  int cur = 0;
  for (int t = 0; t < 23; t++) {
    STAGE(cur ^ 1, (t + 1) * 32);
    COMPUTE(cur);
    __syncthreads();
    cur ^= 1;
  }
  COMPUTE(cur);

  // epilogue: rowsum over this block's 128 h of relu(v + b1[h]) * w2[h]
  float rsum[4][4];
  #pragma unroll
  for (int fm = 0; fm < 4; fm++) {
    float rs[4] = {0.f, 0.f, 0.f, 0.f};
    #pragma unroll
    for (int fn = 0; fn < 4; fn++) {
      const int h = h0 + wc * 64 + fn * 16 + r;
      const float bv = gate_b1[h];
      const float wv = gate_w2[h];
      #pragma unroll
      for (int q = 0; q < 4; q++)
        rs[q] += fmaxf(acc[fm][fn][q] + bv, 0.f) * wv;
    }
    #pragma unroll
    for (int q = 0; q < 4; q++) {
      #pragma unroll
      for (int m = 1; m < 16; m <<= 1) rs[q] += __shfl_xor(rs[q], m);
      rsum[fm][q] = rs[q];
    }
  }
  float* red = (float*)&Asub[0][0];
  __syncthreads();
  if (wc == 1 && r == 0) {
    #pragma unroll
    for (int fm = 0; fm < 4; fm++)
      #pragma unroll
      for (int q = 0; q < 4; q++)
        red[wr * 64 + fm * 16 + g * 4 + q] = rsum[fm][q];
  }
  __syncthreads();
  if (wc == 0 && r == 0) {
    #pragma unroll
    for (int fm = 0; fm < 4; fm++)
      #pragma unroll
      for (int q = 0; q < 4; q++) {
        const int i = wr * 64 + fm * 16 + g * 4 + q;
        gpart[(size_t)by * NCELL + n0 + i] = rsum[fm][q] + red[i];
      }
  }
#undef STAGE
#undef COMPUTE
}

// ---------- cv compute: one block per cell, compact value writes only ----------
__global__ __launch_bounds__(192) void k_cv_cell(
    const int* __restrict__ cv_ids, const int* __restrict__ cv_mask,
    const int* __restrict__ cstart, const float* __restrict__ word_emb,
    const float* __restrict__ gpart, const float* __restrict__ gate_b2,
    float* __restrict__ out) {
  const int cell = blockIdx.x, row = blockIdx.y, tid = threadIdx.x;
  const size_t rbase = (size_t)row * ROW_TOK * EMB;
  const int n = row * CELLS + cell;
  float sg = gate_b2[0];
  #pragma unroll
  for (int j = 0; j < HBLK; j++) sg += gpart[(size_t)j * NCELL + n];
  const float gg = 1.f / (1.f + expf(-sg));
  const float4 cn = *(const float4*)&out[rbase + (size_t)(1 + cell) * EMB + tid * 4];
  float4 cg;
  cg.x = cn.x * gg; cg.y = cn.y * gg; cg.z = cn.z * gg; cg.w = cn.w * gg;
  const int* ids = cv_ids + n * CV_LEN;
  const int* msk = cv_mask + n * CV_LEN;
  int pos = cstart[n];
  #pragma unroll
  for (int j = 0; j < CV_LEN; j++) {
    if (msk[j]) {
      const float4 we = *(const float4*)&word_emb[(size_t)ids[j] * EMB + tid * 4];
      float4 v;
      v.x = we.x + cg.x; v.y = we.y + cg.y; v.z = we.z + cg.z; v.w = we.w + cg.w;
      *(float4*)&out[rbase + (size_t)(65 + pos) * EMB + tid * 4] = v;
      pos++;
    }
  }
}

extern "C" void kernel_launch(void* const* d_in, const int* in_sizes, int n_in,
                              void* d_out, int out_size, void* d_ws, size_t ws_size,
                              hipStream_t stream) {
  const int* cn_ids    = (const int*)d_in[0];
  const int* cn_mask   = (const int*)d_in[1];
  const int* c_types   = (const int*)d_in[2];
  const int* cv_ids    = (const int*)d_in[3];
  const int* cv_mask   = (const int*)d_in[4];
  const float* word_emb = (const float*)d_in[5];
  const float* type_emb = (const float*)d_in[6];
  const float* fuse_w1  = (const float*)d_in[7];
  const float* fuse_b1  = (const float*)d_in[8];
  const float* fuse_w2  = (const float*)d_in[9];
  const float* fuse_b2  = (const float*)d_in[10];
  const float* gate_w1  = (const float*)d_in[11];
  const float* gate_b1  = (const float*)d_in[12];
  const float* gate_w2  = (const float*)d_in[13];
  const float* gate_b2  = (const float*)d_in[14];
  const float* cls_w    = (const float*)d_in[15];

  char* ws = (char*)d_ws;
  float* fpart = (float*)(ws + OFF_FPART);
  float* gpart = (float*)(ws + OFF_GPART);
  unsigned char* cnb = (unsigned char*)(ws + OFF_CNB);
  unsigned char* w1t = (unsigned char*)(ws + OFF_W1T);
  int*   cst   = (int*)(ws + OFF_CST);
  int*   cntp  = (int*)(ws + OFF_CNT);
  float* out   = (float*)d_out;

  k_prep<<<160, 512, 0, stream>>>(type_emb, fuse_w1, fuse_b1, fuse_w2,
                                  fpart, cv_mask, cst, cntp);
  k_cn<<<NCELL + 768, 192, 0, stream>>>(cn_ids, cn_mask, c_types, word_emb,
                                        type_emb, cls_w, fpart, fuse_b2,
                                        gate_w1, w1t, cnb, out);
  k_gate_gemm<<<768 + ROWS * FILL_CHUNKS, 256, 0, stream>>>(
      cnb, w1t, gate_b1, gate_w2, gpart, cntp, out);
  k_cv_cell<<<dim3(CELLS, ROWS), 192, 0, stream>>>(cv_ids, cv_mask, cst,
                                                   word_emb, gpart, gate_b2, out);
}

// Round 12
// 110.793 us; speedup vs baseline: 1.0547x; 1.0547x over previous
//
#include <hip/hip_runtime.h>
#include <hip/hip_bf16.h>

#define ROWS 64
#define CELLS 64
#define CN_LEN 8
#define CV_LEN 16
#define EMB 768
#define HID 3072
#define NCELL 4096
#define L_CV 1024
#define ROW_TOK 1089  /* 1 cls + 64 cn + 1024 cv */
#define HBLK 24       /* 3072/128 h-blocks in gate GEMM */
#define FILL_CHUNKS 96 /* per-row flat fill chunks of 8192 floats */

// ---- workspace layout (bytes), no zero-init required anywhere ----
#define OFF_FPART 0UL                             /* 96*8 f32 fgate partials */
#define OFF_GPART (OFF_FPART + 96UL*8*4)          /* 24*4096 f32 gemm partials */
#define OFF_CNB   (OFF_GPART + 24UL*4096*4)       /* 4096x768 bf16 */
#define OFF_W1T   (OFF_CNB + 4096UL*768*2)        /* 3072x768 bf16 (gate_w1^T) */
#define OFF_CST   (OFF_W1T + 3072UL*768*2)        /* 4096 int per-cell start */
#define OFF_CNT   (OFF_CST + 4096UL*4)            /* 64 int per-row count */

typedef __attribute__((ext_vector_type(8))) short bf16x8;
typedef __attribute__((ext_vector_type(4))) float f32x4;

static __device__ __forceinline__ short f2bf(float x) {
  unsigned u = __float_as_uint(x);
  unsigned r = (u + 0x7fffu + ((u >> 16) & 1u)) >> 16;
  return (short)r;
}

static __device__ __forceinline__ void gload16(const void* g, void* l) {
  __builtin_amdgcn_global_load_lds(
      (const __attribute__((address_space(1))) unsigned*)g,
      (__attribute__((address_space(3))) unsigned*)l, 16, 0, 0);
}

// ---------- prep: blocks 0..95 fgate partials | 96..159 cv prefix ----------
__global__ __launch_bounds__(512) void k_prep(
    const float* __restrict__ type_emb, const float* __restrict__ fuse_w1,
    const float* __restrict__ fuse_b1, const float* __restrict__ fuse_w2,
    float* __restrict__ fpart, const int* __restrict__ cv_mask,
    int* __restrict__ cstart, int* __restrict__ cnt) {
  const int tid = threadIdx.x;
  const int b = blockIdx.x;
  if (b >= 96) {
    // ---- prefix scan over one row's 1024 cv_mask values ----
    __shared__ int ssum[512];
    const int row = b - 96;
    const int base = row * L_CV + tid * 2;
    const int m0 = cv_mask[base], m1 = cv_mask[base + 1];
    const int s = m0 + m1;
    ssum[tid] = s;
    __syncthreads();
    for (int off = 1; off < 512; off <<= 1) {
      int v = (tid >= off) ? ssum[tid - off] : 0;
      __syncthreads();
      ssum[tid] += v;
      __syncthreads();
    }
    if ((tid & 7) == 0) cstart[row * CELLS + (tid >> 3)] = ssum[tid] - s;
    if (tid == 511) cnt[row] = ssum[511];
    return;
  }
  // ---- fgate: 8-type register reuse, w1 read once ----
  __shared__ float te[8 * EMB];      // 24 KB
  __shared__ float red[16][8][33];
  for (int i = tid; i < 8 * EMB; i += 512) te[i] = type_emb[i];
  __syncthreads();
  const int hl = tid & 31, eg = tid >> 5;  // eg in 0..15, 48 e's each
  const int h = b * 32 + hl;
  float acc[8] = {0.f, 0.f, 0.f, 0.f, 0.f, 0.f, 0.f, 0.f};
  const float* wp = fuse_w1 + h;
  #pragma unroll 4
  for (int i = 0; i < 48; i++) {
    const int e = eg * 48 + i;
    const float wv = wp[(size_t)e * HID];
    #pragma unroll
    for (int t = 0; t < 8; t++) acc[t] += te[t * EMB + e] * wv;
  }
  #pragma unroll
  for (int t = 0; t < 8; t++) red[eg][t][hl] = acc[t];
  __syncthreads();
  if (tid < 256) {
    const int t = tid >> 5, h2 = tid & 31;
    float a = fuse_b1[b * 32 + h2];
    #pragma unroll
    for (int e2 = 0; e2 < 16; e2++) a += red[e2][t][h2];
    float v = fmaxf(a, 0.f) * fuse_w2[b * 32 + h2];
    #pragma unroll
    for (int m = 1; m < 32; m <<= 1) v += __shfl_xor(v, m);
    if (h2 == 0) fpart[b * 8 + t] = v;  // each slot written once
  }
}

// ---------- cn_e (blocks 0..4095) + w1t transpose (blocks 4096..4863) ----------
__global__ __launch_bounds__(192) void k_cn(
    const int* __restrict__ cn_ids, const int* __restrict__ cn_mask,
    const int* __restrict__ c_types, const float* __restrict__ word_emb,
    const float* __restrict__ type_emb, const float* __restrict__ cls_w,
    const float* __restrict__ fpart, const float* __restrict__ fuse_b2,
    const float* __restrict__ w1, short* __restrict__ w1t,
    short* __restrict__ cnb, float* __restrict__ out) {
  __shared__ float tile[32][97];
  const int tid = threadIdx.x;
  if (blockIdx.x >= NCELL) {
    // ---- w1t: transpose+bf16 a 96(h) x 32(e) region ----
    const int wb = blockIdx.x - NCELL;
    const int ht = wb & 31, et = wb >> 5;   // ht: 96-wide h tile, et: 32-wide e tile
    const int hi = tid >= 96 ? 1 : 0, cc = tid - 96 * hi;
    #pragma unroll
    for (int i = 0; i < 16; i++) {
      const int rr = i * 2 + hi;
      tile[rr][cc] = w1[(size_t)(et * 32 + rr) * HID + ht * 96 + cc];
    }
    __syncthreads();
    const int rfrac = tid >> 5, cc2 = tid & 31;
    #pragma unroll
    for (int i = 0; i < 16; i++) {
      const int rr2 = i * 6 + rfrac;
      w1t[(size_t)(ht * 96 + rr2) * EMB + et * 32 + cc2] = f2bf(tile[cc2][rr2]);
    }
    return;
  }
  const int n = blockIdx.x;
  const int row = n >> 6, cell = n & 63;
  const int* ids = cn_ids + n * CN_LEN;
  const int* msk = cn_mask + n * CN_LEN;
  float4 s = {0.f, 0.f, 0.f, 0.f};
  int cnt = 0;
  #pragma unroll
  for (int j = 0; j < CN_LEN; j++) {
    if (msk[j]) {
      cnt++;
      const float4 v = *(const float4*)&word_emb[(size_t)ids[j] * EMB + tid * 4];
      s.x += v.x; s.y += v.y; s.z += v.z; s.w += v.w;
    }
  }
  const float inv = 1.f / (float)cnt;
  const int t = c_types[n];
  float sg = fuse_b2[0];
  #pragma unroll 8
  for (int j = 0; j < 96; j++) sg += fpart[j * 8 + t];
  const float fg = 1.f / (1.f + expf(-sg));
  const float4 d = *(const float4*)&type_emb[(size_t)t * EMB + tid * 4];
  float4 c;
  c.x = s.x * inv + d.x * fg;
  c.y = s.y * inv + d.y * fg;
  c.z = s.z * inv + d.z * fg;
  c.w = s.w * inv + d.w * fg;
  short4 b;
  b.x = f2bf(c.x); b.y = f2bf(c.y); b.z = f2bf(c.z); b.w = f2bf(c.w);
  *(short4*)&cnb[(size_t)n * EMB + tid * 4] = b;
  *(float4*)&out[(size_t)row * ROW_TOK * EMB + (size_t)(1 + cell) * EMB + tid * 4] = c;
  if (cell == 0)
    *(float4*)&out[(size_t)row * ROW_TOK * EMB + tid * 4] =
        *(const float4*)&cls_w[tid * 4];
}

// ---------- gate GEMM (blocks 0..767) + cv tail zero-fill (768.., backfills) ----------
__global__ __launch_bounds__(256) void k_gate_gemm(
    const short* __restrict__ cnb, const short* __restrict__ w1t,
    const float* __restrict__ gate_b1, const float* __restrict__ gate_w2,
    float* __restrict__ gpart, const int* __restrict__ cnt,
    float* __restrict__ out) {
  __shared__ short Asub[2][128 * 32];   // 2 x 8 KB
  __shared__ short Bsub[2][128 * 32];   // 2 x 8 KB
  const int tid = threadIdx.x;
  if (blockIdx.x >= 768) {
    // ---- flat zero-fill of cv tail: row, 8192-float chunk ----
    const int fb = blockIdx.x - 768;
    const int row = fb / FILL_CHUNKS, chunk = fb % FILL_CHUNKS;
    const int lim = cnt[row] * EMB;            // fill floats at idx >= lim
    const int c0 = chunk * 8192;
    if (c0 + 8192 <= lim) return;              // chunk entirely value-covered
    const size_t base = (size_t)row * ROW_TOK * EMB + 65UL * EMB;
    const float4 z = {0.f, 0.f, 0.f, 0.f};
    #pragma unroll
    for (int i = 0; i < 8; i++) {
      const int idx = c0 + i * 1024 + tid * 4;
      if (idx >= lim) *(float4*)&out[base + idx] = z;
    }
    return;
  }
  // bijective XCD swizzle: 768 blocks, 96 consecutive per XCD -> same-by chunks
  const int orig = blockIdx.x;
  const int wgid = (orig & 7) * 96 + (orig >> 3);
  const int bx = wgid & 31, by = wgid >> 5;   // bx: n-tile 0..31, by: h-tile 0..23
  const int n0 = bx * 128, h0 = by * 128;
  const int lane = tid & 63, w = tid >> 6;
  const int wr = w >> 1, wc = w & 1;
  const int r = lane & 15, g = lane >> 4;
  f32x4 acc[4][4];
  #pragma unroll
  for (int a = 0; a < 4; a++)
    #pragma unroll
    for (int b = 0; b < 4; b++) acc[a][b] = (f32x4)0.f;

  const int s0 = tid, s1 = tid + 256;
  const int ar0 = s0 >> 2, ac0 = (s0 & 3) * 8;
  const int ar1 = s1 >> 2, ac1 = (s1 & 3) * 8;
  const short* aB = cnb + (size_t)n0 * EMB;
  const short* bB = w1t + (size_t)h0 * EMB;

#define STAGE(buf, kk)                                                  \
  do {                                                                  \
    gload16(aB + (size_t)ar0 * EMB + (kk) + ac0, &Asub[buf][s0 * 8]);   \
    gload16(aB + (size_t)ar1 * EMB + (kk) + ac1, &Asub[buf][s1 * 8]);   \
    gload16(bB + (size_t)ar0 * EMB + (kk) + ac0, &Bsub[buf][s0 * 8]);   \
    gload16(bB + (size_t)ar1 * EMB + (kk) + ac1, &Bsub[buf][s1 * 8]);   \
  } while (0)

#define COMPUTE(buf)                                                          \
  do {                                                                        \
    bf16x8 fa[4], fb[4];                                                      \
    _Pragma("unroll")                                                         \
    for (int fm = 0; fm < 4; fm++)                                            \
      fa[fm] = *(const bf16x8*)&Asub[buf][(wr * 64 + fm * 16 + r) * 32 + g * 8]; \
    _Pragma("unroll")                                                         \
    for (int fn = 0; fn < 4; fn++)                                            \
      fb[fn] = *(const bf16x8*)&Bsub[buf][(wc * 64 + fn * 16 + r) * 32 + g * 8]; \
    _Pragma("unroll")                                                         \
    for (int fm = 0; fm < 4; fm++)                                            \
      _Pragma("unroll")                                                       \
      for (int fn = 0; fn < 4; fn++)                                          \
        acc[fm][fn] = __builtin_amdgcn_mfma_f32_16x16x32_bf16(                \
            fa[fm], fb[fn], acc[fm][fn], 0, 0, 0);                            \
  } while (0)

  STAGE(0, 0);
  __syncthreads();
  int cur = 0;
  for (int t = 0; t < 23; t++) {
    STAGE(cur ^ 1, (t + 1) * 32);
    COMPUTE(cur);
    __syncthreads();
    cur ^= 1;
  }
  COMPUTE(cur);

  // epilogue: rowsum over this block's 128 h of relu(v + b1[h]) * w2[h]
  float rsum[4][4];
  #pragma unroll
  for (int fm = 0; fm < 4; fm++) {
    float rs[4] = {0.f, 0.f, 0.f, 0.f};
    #pragma unroll
    for (int fn = 0; fn < 4; fn++) {
      const int h = h0 + wc * 64 + fn * 16 + r;
      const float bv = gate_b1[h];
      const float wv = gate_w2[h];
      #pragma unroll
      for (int q = 0; q < 4; q++)
        rs[q] += fmaxf(acc[fm][fn][q] + bv, 0.f) * wv;
    }
    #pragma unroll
    for (int q = 0; q < 4; q++) {
      #pragma unroll
      for (int m = 1; m < 16; m <<= 1) rs[q] += __shfl_xor(rs[q], m);
      rsum[fm][q] = rs[q];
    }
  }
  float* red = (float*)&Asub[0][0];
  __syncthreads();
  if (wc == 1 && r == 0) {
    #pragma unroll
    for (int fm = 0; fm < 4; fm++)
      #pragma unroll
      for (int q = 0; q < 4; q++)
        red[wr * 64 + fm * 16 + g * 4 + q] = rsum[fm][q];
  }
  __syncthreads();
  if (wc == 0 && r == 0) {
    #pragma unroll
    for (int fm = 0; fm < 4; fm++)
      #pragma unroll
      for (int q = 0; q < 4; q++) {
        const int i = wr * 64 + fm * 16 + g * 4 + q;
        gpart[(size_t)by * NCELL + n0 + i] = rsum[fm][q] + red[i];
      }
  }
#undef STAGE
#undef COMPUTE
}

// ---------- cv compute: one block per cell, compact value writes only ----------
__global__ __launch_bounds__(192) void k_cv_cell(
    const int* __restrict__ cv_ids, const int* __restrict__ cv_mask,
    const int* __restrict__ cstart, const float* __restrict__ word_emb,
    const float* __restrict__ gpart, const float* __restrict__ gate_b2,
    float* __restrict__ out) {
  const int cell = blockIdx.x, row = blockIdx.y, tid = threadIdx.x;
  const size_t rbase = (size_t)row * ROW_TOK * EMB;
  const int n = row * CELLS + cell;
  float sg = gate_b2[0];
  #pragma unroll
  for (int j = 0; j < HBLK; j++) sg += gpart[(size_t)j * NCELL + n];
  const float gg = 1.f / (1.f + expf(-sg));
  const float4 cn = *(const float4*)&out[rbase + (size_t)(1 + cell) * EMB + tid * 4];
  float4 cg;
  cg.x = cn.x * gg; cg.y = cn.y * gg; cg.z = cn.z * gg; cg.w = cn.w * gg;
  const int* ids = cv_ids + n * CV_LEN;
  const int* msk = cv_mask + n * CV_LEN;
  int pos = cstart[n];
  #pragma unroll
  for (int j = 0; j < CV_LEN; j++) {
    if (msk[j]) {
      const float4 we = *(const float4*)&word_emb[(size_t)ids[j] * EMB + tid * 4];
      float4 v;
      v.x = we.x + cg.x; v.y = we.y + cg.y; v.z = we.z + cg.z; v.w = we.w + cg.w;
      *(float4*)&out[rbase + (size_t)(65 + pos) * EMB + tid * 4] = v;
      pos++;
    }
  }
}

extern "C" void kernel_launch(void* const* d_in, const int* in_sizes, int n_in,
                              void* d_out, int out_size, void* d_ws, size_t ws_size,
                              hipStream_t stream) {
  const int* cn_ids    = (const int*)d_in[0];
  const int* cn_mask   = (const int*)d_in[1];
  const int* c_types   = (const int*)d_in[2];
  const int* cv_ids    = (const int*)d_in[3];
  const int* cv_mask   = (const int*)d_in[4];
  const float* word_emb = (const float*)d_in[5];
  const float* type_emb = (const float*)d_in[6];
  const float* fuse_w1  = (const float*)d_in[7];
  const float* fuse_b1  = (const float*)d_in[8];
  const float* fuse_w2  = (const float*)d_in[9];
  const float* fuse_b2  = (const float*)d_in[10];
  const float* gate_w1  = (const float*)d_in[11];
  const float* gate_b1  = (const float*)d_in[12];
  const float* gate_w2  = (const float*)d_in[13];
  const float* gate_b2  = (const float*)d_in[14];
  const float* cls_w    = (const float*)d_in[15];

  char* ws = (char*)d_ws;
  float* fpart = (float*)(ws + OFF_FPART);
  float* gpart = (float*)(ws + OFF_GPART);
  short* cnb   = (short*)(ws + OFF_CNB);
  short* w1t   = (short*)(ws + OFF_W1T);
  int*   cst   = (int*)(ws + OFF_CST);
  int*   cntp  = (int*)(ws + OFF_CNT);
  float* out   = (float*)d_out;

  k_prep<<<160, 512, 0, stream>>>(type_emb, fuse_w1, fuse_b1, fuse_w2,
                                  fpart, cv_mask, cst, cntp);
  k_cn<<<NCELL + 768, 192, 0, stream>>>(cn_ids, cn_mask, c_types, word_emb,
                                        type_emb, cls_w, fpart, fuse_b2,
                                        gate_w1, w1t, cnb, out);
  k_gate_gemm<<<768 + ROWS * FILL_CHUNKS, 256, 0, stream>>>(
      cnb, w1t, gate_b1, gate_w2, gpart, cntp, out);
  k_cv_cell<<<dim3(CELLS, ROWS), 192, 0, stream>>>(cv_ids, cv_mask, cst,
                                                   word_emb, gpart, gate_b2, out);
}